// Round 5
// baseline (1664.107 us; speedup 1.0000x reference)
//
#include <hip/hip_runtime.h>

#define NB 256
#define NT 256

typedef __attribute__((ext_vector_type(8))) short short8;
typedef __attribute__((ext_vector_type(4))) float f32x4;
typedef __attribute__((ext_vector_type(2))) unsigned long long ull2;

constexpr int Bz = 64, Sz = 256, Tz = 32, Ez = 512, Hz = 512, G4 = 2048, VT = 32000;

__device__ __forceinline__ unsigned short f2b(float f) {
    unsigned u; __builtin_memcpy(&u, &f, 4);
    u = (u + 0x7fffu + ((u >> 16) & 1u)) >> 16;   // RNE fp32 -> bf16
    return (unsigned short)u;
}
__device__ __forceinline__ float sgm(float x) { return 1.0f / (1.0f + __expf(-x)); }
__device__ __forceinline__ float tnh(float x) { return 1.0f - 2.0f / (1.0f + __expf(2.0f * x)); }

// ===================== 0) workspace init (stream-ordered before scan) =====================
__global__ __launch_bounds__(NT) void init_kernel(
    unsigned* __restrict__ hbuf_u32, float* __restrict__ row_sums,
    unsigned* __restrict__ bars)
{
    const int idx = blockIdx.x * NT + threadIdx.x;     // 64 blocks: covers 65536 words
#pragma unroll
    for (int i = 0; i < 4; ++i) hbuf_u32[idx * 4 + i] = 0u;
    if (blockIdx.x == 0) {
        bars[threadIdx.x] = 0u;                        // 1 KB barrier state
        if (threadIdx.x < 64) row_sums[threadIdx.x] = 0.0f;
    }
}

// ===================== 1) cooperative LSTM scan =====================
// h exchange rides relaxed agent-scope atomics (LLC-coherent).
// Barrier: round-4 PROVEN flavor (flat counter + flag + tid0 s_sleep poll) — unchanged.
// New: L0's embedding x-staging is prestaged in the pre-barrier shadow (tokens are
// pure inputs), so post-barrier L0 stages only the h-half.
__global__ __launch_bounds__(NT, 2) void scan_kernel(
    const int* __restrict__ X, const int* __restrict__ Y,
    const float* __restrict__ emb_src, const float* __restrict__ emb_tgt,
    const float* __restrict__ eWih, const float* __restrict__ eWhh,
    const float* __restrict__ ebih, const float* __restrict__ ebhh,
    const float* __restrict__ dWih, const float* __restrict__ dWhh,
    const float* __restrict__ dbih, const float* __restrict__ dbhh,
    unsigned short* __restrict__ hbuf,   // [2 layer][2 parity][64][512] bf16
    unsigned* __restrict__ bars)         // [4 groups][64 u32]: +0 arrive, +32 flag
{
    __shared__ __align__(16) unsigned char smem[39168];
    unsigned short* xh_lds = (unsigned short*)smem;          // [16][1024] bf16, 16B chunks XOR-swizzled by (row&7)
    float* gates_lds = (float*)(smem + 32768);               // [4][16][20] fp32 (pad 16->20)
    float* c_lds     = (float*)(smem + 37888);               // [16][20] fp32, persists enc->dec

    const int tid  = threadIdx.x;
    const int bid  = blockIdx.x;
    const int lay  = bid >> 7;         // 0 or 1 (pipeline stage = LSTM layer)
    const int bt   = (bid >> 5) & 3;   // batch tile (16 elems)
    const int ht   = bid & 31;         // hidden-unit tile (16 units)
    const int wave = tid >> 6;         // gate index: 0=i 1=f 2=g 3=o
    const int lane = tid & 63;
    const int nl   = lane & 15;
    const int quad = lane >> 4;

    unsigned* bar_arrive = bars + bt * 64;
    unsigned* bar_flag   = bars + bt * 64 + 32;
    unsigned gen = 0;

    auto barrier = [&]() {
        ++gen;
        __syncthreads();   // drains every wave's vmcnt -> h stores are at LLC
        if (tid == 0) {
            unsigned old = __hip_atomic_fetch_add(bar_arrive, 1u,
                               __ATOMIC_RELAXED, __HIP_MEMORY_SCOPE_AGENT);
            if (old == gen * 64u - 1u) {
                __hip_atomic_store(bar_flag, gen,
                                   __ATOMIC_RELAXED, __HIP_MEMORY_SCOPE_AGENT);
            } else {
                while (__hip_atomic_load(bar_flag,
                           __ATOMIC_RELAXED, __HIP_MEMORY_SCOPE_AGENT) < gen)
                    __builtin_amdgcn_s_sleep(1);
            }
        }
        __syncthreads();
    };

    for (int i = tid; i < 320; i += NT) c_lds[i] = 0.0f;   // cell states (padded tile)
    __syncthreads();

    // ---- per-wave weight cache in VGPRs: 16 gate-rows x K=1024 (Wih||Whh), bf16 ----
    short8 wfrag[32];
    float bias_r = 0.0f;
    const int r = wave * 512 + ht * 16 + nl;       // global gate-row for this lane

    auto load_w = [&](const float* Wih, const float* Whh,
                      const float* bih, const float* bhh) {
        const float* wi = Wih + (size_t)(lay * G4 + r) * 512;
        const float* wh = Whh + (size_t)(lay * G4 + r) * 512;
#pragma unroll
        for (int kc = 0; kc < 32; ++kc) {
            const int k0 = kc * 32 + quad * 8;
            const float* s = (k0 < 512) ? (wi + k0) : (wh + (k0 - 512));
            short8 v;
#pragma unroll
            for (int j = 0; j < 8; ++j) v[j] = (short)f2b(s[j]);
            wfrag[kc] = v;
        }
        bias_r = bih[lay * G4 + r] + bhh[lay * G4 + r];
    };

    // A-read swizzle constants: physical chunk = (4*kc|quad) ^ (nl&7)
    //   chunk bits 0-1:  quad ^ (nl&3)          (qx)
    //   chunk bit 2 (kc bit0): kc ^ ((nl>>2)&1) (kx) -> fold into two base ptrs (+-32 shorts)
    const int kx = (nl >> 2) & 1;
    const int qx = quad ^ (nl & 3);

    // ---- staging helpers. Wave w owns rows 4w..4w+3; lane l handles 16B chunk l,
    //      stored at chunk l^(row&7) (conflict-free ds_write_b128). ----
    auto stage_h = [&](const unsigned short* hrow) {          // h half (post-barrier)
        const int rb = wave << 2;
#pragma unroll
        for (int rr = 0; rr < 4; ++rr) {
            const int rw = rb + rr;
            const unsigned long long* s =
                (const unsigned long long*)(hrow + ((size_t)(bt * 16 + rw) << 9)) + (lane << 1);
            unsigned long long a = __hip_atomic_load(s,
                    __ATOMIC_RELAXED, __HIP_MEMORY_SCOPE_AGENT);
            unsigned long long b = __hip_atomic_load(s + 1,
                    __ATOMIC_RELAXED, __HIP_MEMORY_SCOPE_AGENT);
            *(ull2*)(xh_lds + (rw << 10) + 512 + ((lane ^ (rw & 7)) << 3)) = (ull2){a, b};
        }
    };
    auto stage_xb = [&](const unsigned short* xb) {           // L1 x half = h0 (post-barrier)
        const int rb = wave << 2;
#pragma unroll
        for (int rr = 0; rr < 4; ++rr) {
            const int rw = rb + rr;
            const unsigned long long* s =
                (const unsigned long long*)(xb + ((size_t)(bt * 16 + rw) << 9)) + (lane << 1);
            unsigned long long a = __hip_atomic_load(s,
                    __ATOMIC_RELAXED, __HIP_MEMORY_SCOPE_AGENT);
            unsigned long long b = __hip_atomic_load(s + 1,
                    __ATOMIC_RELAXED, __HIP_MEMORY_SCOPE_AGENT);
            *(ull2*)(xh_lds + (rw << 10) + ((lane ^ (rw & 7)) << 3)) = (ull2){a, b};
        }
    };
    // L0 x half: embedding rows for the NEXT step, written in the pre-barrier shadow.
    // Safe: runs after the gate-scatter __syncthreads (all MFMA reads of x done);
    // overlaps h-store drain + arrive + flag poll.
    auto prestage_x = [&](const float* xtab, const int* tok, int stride, int col, int bos) {
        const int rb = wave << 2;
        int tk[4];
#pragma unroll
        for (int rr = 0; rr < 4; ++rr)
            tk[rr] = bos ? 2 : tok[(bt * 16 + rb + rr) * stride + col];
#pragma unroll
        for (int rr = 0; rr < 4; ++rr) {
            const int rw = rb + rr;
            const float* s = xtab + (size_t)tk[rr] * Ez + (lane << 3);
            float4 lo = *(const float4*)s;
            float4 hi = *(const float4*)(s + 4);
            short8 v;
            v[0] = (short)f2b(lo.x); v[1] = (short)f2b(lo.y);
            v[2] = (short)f2b(lo.z); v[3] = (short)f2b(lo.w);
            v[4] = (short)f2b(hi.x); v[5] = (short)f2b(hi.y);
            v[6] = (short)f2b(hi.z); v[7] = (short)f2b(hi.w);
            *(short8*)(xh_lds + (rw << 10) + ((lane ^ (rw & 7)) << 3)) = v;
        }
    };

    // gates[16 batch][16 rows] for this wave's gate, K=1024; 4 parallel acc chains.
    auto mfma_tail = [&](unsigned short* hout) {
        const unsigned short* arE = xh_lds + (nl << 10) + (qx << 3) + (kx << 5);
        const unsigned short* arO = xh_lds + (nl << 10) + (qx << 3) - (kx << 5);
        f32x4 a0 = {0.f, 0.f, 0.f, 0.f}, a1 = a0, a2 = a0, a3 = a0;
#pragma unroll
        for (int kc = 0; kc < 32; kc += 4) {
            short8 x0 = *(const short8*)(arE + ((kc + 0) << 5));
            short8 x1 = *(const short8*)(arO + ((kc + 1) << 5));
            short8 x2 = *(const short8*)(arE + ((kc + 2) << 5));
            short8 x3 = *(const short8*)(arO + ((kc + 3) << 5));
            a0 = __builtin_amdgcn_mfma_f32_16x16x32_bf16(x0, wfrag[kc + 0], a0, 0, 0, 0);
            a1 = __builtin_amdgcn_mfma_f32_16x16x32_bf16(x1, wfrag[kc + 1], a1, 0, 0, 0);
            a2 = __builtin_amdgcn_mfma_f32_16x16x32_bf16(x2, wfrag[kc + 2], a2, 0, 0, 0);
            a3 = __builtin_amdgcn_mfma_f32_16x16x32_bf16(x3, wfrag[kc + 3], a3, 0, 0, 0);
        }
        f32x4 acc = (a0 + a1) + (a2 + a3);
        // C/D: col(n)=lane&15, row(m)=quad*4+i.  Activate + scatter to LDS.
#pragma unroll
        for (int i = 0; i < 4; ++i) {
            float v = acc[i] + bias_r;
            v = (wave == 2) ? tnh(v) : sgm(v);
            gates_lds[wave * 320 + (quad * 4 + i) * 20 + nl] = v;
        }
        __syncthreads();
        if (tid < 128) {   // c/h update: (batch m, unit pair np) per thread
            const int m = tid >> 3, np = tid & 7;
            float hp[2];
#pragma unroll
            for (int j = 0; j < 2; ++j) {
                const int n = 2 * np + j;
                const float iv = gates_lds[      m * 20 + n];
                const float fv = gates_lds[320 + m * 20 + n];
                const float gv = gates_lds[640 + m * 20 + n];
                const float ov = gates_lds[960 + m * 20 + n];
                float c = c_lds[m * 20 + n];
                c = fv * c + iv * gv;
                c_lds[m * 20 + n] = c;
                hp[j] = ov * tnh(c);
            }
            const unsigned pack = (unsigned)f2b(hp[0]) | ((unsigned)f2b(hp[1]) << 16);
            unsigned* dst = (unsigned*)&hout[(size_t)(bt * 16 + m) * 512 + ht * 16 + 2 * np];
            __hip_atomic_store(dst, pack, __ATOMIC_RELAXED, __HIP_MEMORY_SCOPE_AGENT);
        }
    };

    auto hb = [&](int l, int p) { return hbuf + (size_t)(l * 2 + p) * Bz * Hz; };

    // ===== encoder: pipelined rounds; L0 does step t, L1 does step t-1 =====
    load_w(eWih, eWhh, ebih, ebhh);
    if (lay == 0) prestage_x(emb_src, X, Sz, 0, 0);          // x(0) before first round
    for (int t = 0; t <= Sz; ++t) {
        if (lay == 0) {
            if (t < Sz) {
                stage_h(hb(0, (t + 1) & 1));
                __syncthreads();
                mfma_tail(hb(0, t & 1));
                if (t + 1 < Sz) prestage_x(emb_src, X, Sz, t + 1, 0);
                else            prestage_x(emb_tgt, nullptr, 0, 0, 1);  // decoder BOS row
            } else {
                load_w(dWih, dWhh, dbih, dbhh);  // idle round: swap weights early
            }
        } else {
            if (t >= 1) {
                const int s = t - 1;
                stage_xb(hb(0, s & 1));
                stage_h(hb(1, (s + 1) & 1));
                __syncthreads();
                mfma_tail(hb(1, s & 1));
            }
        }
        barrier();
    }

    // ===== decoder (states carry over: h via buffer parity, c in LDS) =====
    if (lay == 1) load_w(dWih, dWhh, dbih, dbhh);
    for (int t = 0; t <= Tz; ++t) {
        if (lay == 0) {
            if (t < Tz) {
                stage_h(hb(0, (t + 1) & 1));
                __syncthreads();
                mfma_tail(hb(0, t & 1));
                // x(t+1) = emb_tgt[Y[:, t]]  (dec_in = [BOS, y[:, :T-1]])
                if (t + 1 < Tz) prestage_x(emb_tgt, Y, Tz, t, 0);
            }
        } else {
            if (t >= 1) {
                const int s = t - 1;
                stage_xb(hb(0, s & 1));
                stage_h(hb(1, (s + 1) & 1));
                __syncthreads();
                mfma_tail(hb(1, s & 1));
            }
        }
        if (t < Tz) barrier();   // final round needs no barrier (kernel boundary syncs)
    }
    // decoder L1 final h sits in hb(1,1); FC kernel reads it (kernel-boundary sync).
}

// ===================== 2) FC [64 x 32000] + exp-sum =====================
__global__ __launch_bounds__(NT, 1) void fc_kernel(
    const float* __restrict__ fcW, const float* __restrict__ fcb,
    const unsigned short* __restrict__ hbuf,
    float* __restrict__ logits, float* __restrict__ row_sums)
{
    __shared__ __align__(16) unsigned char smem[66816];
    unsigned short* h_lds = (unsigned short*)smem;          // [64][520] bf16
    float* row_part = (float*)(smem + 64 * 520 * 2);        // [64]

    const int tid  = threadIdx.x;
    const int bid  = blockIdx.x;
    const int wave = tid >> 6;
    const int lane = tid & 63;
    const int nl   = lane & 15;
    const int quad = lane >> 4;

    {   // stage top hidden: hb(1,1) = hbuf + 3*64*512
        const unsigned short* htop = hbuf + (size_t)3 * Bz * Hz;
        const int rr2 = tid >> 2, pp = tid & 3;
        const short8* s = (const short8*)(htop + rr2 * 512 + pp * 128);
        short8* d = (short8*)(h_lds + rr2 * 520 + pp * 128);
#pragma unroll
        for (int i = 0; i < 16; ++i) d[i] = s[i];
    }
    if (tid < 64) row_part[tid] = 0.f;
    __syncthreads();

    const int c0 = bid * 128;                 // this block's 128 vocab cols
    f32x4 acc[8];
#pragma unroll
    for (int ct = 0; ct < 8; ++ct) acc[ct] = (f32x4){0.f, 0.f, 0.f, 0.f};
    const unsigned short* ar = h_lds + (wave * 16 + nl) * 520 + quad * 8;
    const float* bb = fcW + ((size_t)c0 + nl) * 512 + quad * 8;
    for (int kc = 0; kc < 16; ++kc) {
        short8 a = *(const short8*)(ar + kc * 32);
#pragma unroll
        for (int ct = 0; ct < 8; ++ct) {
            const float* bp = bb + (size_t)ct * 16 * 512 + kc * 32;
            float4 lo = *(const float4*)(bp);
            float4 hi = *(const float4*)(bp + 4);
            short8 b;
            b[0] = (short)f2b(lo.x); b[1] = (short)f2b(lo.y);
            b[2] = (short)f2b(lo.z); b[3] = (short)f2b(lo.w);
            b[4] = (short)f2b(hi.x); b[5] = (short)f2b(hi.y);
            b[6] = (short)f2b(hi.z); b[7] = (short)f2b(hi.w);
            acc[ct] = __builtin_amdgcn_mfma_f32_16x16x32_bf16(a, b, acc[ct], 0, 0, 0);
        }
    }
    float ls[4] = {0.f, 0.f, 0.f, 0.f};
#pragma unroll
    for (int ct = 0; ct < 8; ++ct) {
        const int col = c0 + ct * 16 + nl;
        const float bias = fcb[col];
#pragma unroll
        for (int i = 0; i < 4; ++i) {
            const float lg = acc[ct][i] + bias;
            logits[(size_t)(wave * 16 + quad * 4 + i) * VT + col] = lg;
            ls[i] += __expf(lg);     // |logit| <= ~41 -> no overflow, max-shift unneeded
        }
    }
#pragma unroll
    for (int i = 0; i < 4; ++i)
        atomicAdd(&row_part[wave * 16 + quad * 4 + i], ls[i]);
    __syncthreads();
    if (tid < 64) atomicAdd(&row_sums[tid], row_part[tid]);
}

// ===================== 3) normalize: out = logits - log(sum) =====================
__global__ __launch_bounds__(NT) void norm_kernel(
    const float* __restrict__ logits, const float* __restrict__ row_sums,
    float* __restrict__ out)
{
    const int idx = blockIdx.x * NT + threadIdx.x;   // grid covers 64*32000 exactly
    const int row = idx / VT;
    out[idx] = logits[idx] - __logf(row_sums[row]);
}

extern "C" void kernel_launch(void* const* d_in, const int* in_sizes, int n_in,
                              void* d_out, int out_size, void* d_ws, size_t ws_size,
                              hipStream_t stream) {
    const int* X = (const int*)d_in[0];
    const int* Y = (const int*)d_in[1];
    const float* emb_src = (const float*)d_in[2];
    const float* emb_tgt = (const float*)d_in[3];
    const float* eWih = (const float*)d_in[4];
    const float* eWhh = (const float*)d_in[5];
    const float* ebih = (const float*)d_in[6];
    const float* ebhh = (const float*)d_in[7];
    const float* dWih = (const float*)d_in[8];
    const float* dWhh = (const float*)d_in[9];
    const float* dbih = (const float*)d_in[10];
    const float* dbhh = (const float*)d_in[11];
    const float* fcW = (const float*)d_in[12];
    const float* fcb = (const float*)d_in[13];
    float* out = (float*)d_out;

    // ws layout: [0,256KB) bf16 h buffers; [256KB,+256B) row_sums;
    //            [260KB,+1KB) barrier state; [512KB,+8.192MB) fp32 logits
    unsigned short* hbuf = (unsigned short*)d_ws;
    float* row_sums = (float*)((char*)d_ws + 262144);
    unsigned* bars  = (unsigned*)((char*)d_ws + 266240);
    float* logits   = (float*)((char*)d_ws + 524288);

    init_kernel<<<dim3(64), dim3(NT), 0, stream>>>((unsigned*)hbuf, row_sums, bars);

    void* args[] = {&X, &Y, &emb_src, &emb_tgt, &eWih, &eWhh, &ebih, &ebhh,
                    &dWih, &dWhh, &dbih, &dbhh, &hbuf, &bars};
    hipLaunchCooperativeKernel(reinterpret_cast<void*>(scan_kernel),
                               dim3(NB), dim3(NT), args, 0, stream);

    fc_kernel<<<dim3(VT / 128), dim3(NT), 0, stream>>>(fcW, fcb, hbuf, logits, row_sums);

    norm_kernel<<<dim3((Bz * VT) / NT), dim3(NT), 0, stream>>>(logits, row_sums, out);
}

// Round 6
// 1442.257 us; speedup vs baseline: 1.1538x; 1.1538x over previous
//
#include <hip/hip_runtime.h>

#define NB 256
#define NT 256

typedef __attribute__((ext_vector_type(8))) short short8;
typedef __attribute__((ext_vector_type(4))) float f32x4;
typedef __attribute__((ext_vector_type(2))) unsigned long long ull2;
typedef __attribute__((ext_vector_type(4))) unsigned u32x4;

constexpr int Bz = 64, Sz = 256, Tz = 32, Ez = 512, Hz = 512, G4 = 2048, VT = 32000;

__device__ __forceinline__ unsigned short f2b(float f) {
    unsigned u; __builtin_memcpy(&u, &f, 4);
    u = (u + 0x7fffu + ((u >> 16) & 1u)) >> 16;   // RNE fp32 -> bf16
    return (unsigned short)u;
}
__device__ __forceinline__ float sgm(float x) { return 1.0f / (1.0f + __expf(-x)); }
__device__ __forceinline__ float tnh(float x) { return 1.0f - 2.0f / (1.0f + __expf(2.0f * x)); }
__device__ __forceinline__ unsigned umin2(unsigned a, unsigned b) { return a < b ? a : b; }
__device__ __forceinline__ unsigned min4u(u32x4 v) {
    return umin2(umin2(v.x, v.y), umin2(v.z, v.w));
}

// ===================== 0) workspace init (stream-ordered before scan) =====================
__global__ __launch_bounds__(NT) void init_kernel(
    unsigned* __restrict__ hbuf_u32, float* __restrict__ row_sums,
    unsigned* __restrict__ bars)
{
    const int idx = blockIdx.x * NT + threadIdx.x;     // 64 blocks: covers 65536 words
#pragma unroll
    for (int i = 0; i < 4; ++i) hbuf_u32[idx * 4 + i] = 0u;
    if (blockIdx.x == 0) {
        bars[threadIdx.x] = 0u;                        // [4 groups][64 u32] arrival slots
        if (threadIdx.x < 64) row_sums[threadIdx.x] = 0.0f;
    }
}

// ===================== 1) cooperative LSTM scan =====================
// h exchange rides relaxed agent-scope atomics (LLC-coherent).
// Barrier v3: per-block arrival SLOT stores (no counter RMW, no flag post) +
// single-lane (tid0) min-poll of the 64 packed slots (4x dwordx4, 4 lines,
// 64 requests/line-period across the group -> no LLC congestion).
// Removes one dependent LLC round-trip (counter->flag) per round vs round-4.
__global__ __launch_bounds__(NT, 2) void scan_kernel(
    const int* __restrict__ X, const int* __restrict__ Y,
    const float* __restrict__ emb_src, const float* __restrict__ emb_tgt,
    const float* __restrict__ eWih, const float* __restrict__ eWhh,
    const float* __restrict__ ebih, const float* __restrict__ ebhh,
    const float* __restrict__ dWih, const float* __restrict__ dWhh,
    const float* __restrict__ dbih, const float* __restrict__ dbhh,
    unsigned short* __restrict__ hbuf,   // [2 layer][2 parity][64][512] bf16
    unsigned* __restrict__ bars)         // [4 groups][64 u32] arrival slots (256B/group)
{
    __shared__ __align__(16) unsigned char smem[39168];
    unsigned short* xh_lds = (unsigned short*)smem;          // [16][1024] bf16, 16B chunks XOR-swizzled by (row&7)
    float* gates_lds = (float*)(smem + 32768);               // [4][16][20] fp32 (pad 16->20)
    float* c_lds     = (float*)(smem + 37888);               // [16][20] fp32, persists enc->dec

    const int tid  = threadIdx.x;
    const int bid  = blockIdx.x;
    const int lay  = bid >> 7;         // 0 or 1 (pipeline stage = LSTM layer)
    const int bt   = (bid >> 5) & 3;   // batch tile (16 elems)
    const int ht   = bid & 31;         // hidden-unit tile (16 units)
    const int wave = tid >> 6;         // gate index: 0=i 1=f 2=g 3=o
    const int lane = tid & 63;
    const int nl   = lane & 15;
    const int quad = lane >> 4;

    unsigned* slots = bars + bt * 64;              // 256B-aligned group region
    const int myslot = lay * 32 + ht;              // 0..63
    unsigned gen = 0;

    auto barrier = [&]() {
        ++gen;
        __syncthreads();   // drains every wave's vmcnt -> h stores are at LLC
        if (tid == 0) {
            __hip_atomic_store(slots + myslot, gen,
                               __ATOMIC_RELAXED, __HIP_MEMORY_SCOPE_AGENT);
            for (;;) {
                u32x4 a, b, c, d;
                asm volatile(
                    "global_load_dwordx4 %0, %4, off sc0 sc1\n\t"
                    "global_load_dwordx4 %1, %4, off offset:16 sc0 sc1\n\t"
                    "global_load_dwordx4 %2, %4, off offset:32 sc0 sc1\n\t"
                    "global_load_dwordx4 %3, %4, off offset:48 sc0 sc1\n\t"
                    "s_waitcnt vmcnt(0)"
                    : "=&v"(a), "=&v"(b), "=&v"(c), "=&v"(d)
                    : "v"(slots)
                    : "memory");
                const unsigned m = umin2(umin2(min4u(a), min4u(b)),
                                         umin2(min4u(c), min4u(d)));
                if (m >= gen) break;
            }
        }
        __syncthreads();
    };

    for (int i = tid; i < 320; i += NT) c_lds[i] = 0.0f;   // cell states (padded tile)
    __syncthreads();

    // ---- per-wave weight cache in VGPRs: 16 gate-rows x K=1024 (Wih||Whh), bf16 ----
    short8 wfrag[32];
    float bias_r = 0.0f;
    const int r = wave * 512 + ht * 16 + nl;       // global gate-row for this lane

    auto load_w = [&](const float* Wih, const float* Whh,
                      const float* bih, const float* bhh) {
        const float* wi = Wih + (size_t)(lay * G4 + r) * 512;
        const float* wh = Whh + (size_t)(lay * G4 + r) * 512;
#pragma unroll
        for (int kc = 0; kc < 32; ++kc) {
            const int k0 = kc * 32 + quad * 8;
            const float* s = (k0 < 512) ? (wi + k0) : (wh + (k0 - 512));
            short8 v;
#pragma unroll
            for (int j = 0; j < 8; ++j) v[j] = (short)f2b(s[j]);
            wfrag[kc] = v;
        }
        bias_r = bih[lay * G4 + r] + bhh[lay * G4 + r];
    };

    // A-read swizzle constants: physical chunk = (4*kc|quad) ^ (nl&7)
    //   chunk bits 0-1:  quad ^ (nl&3)          (qx)
    //   chunk bit 2 (kc bit0): kc ^ ((nl>>2)&1) (kx) -> fold into two base ptrs (+-32 shorts)
    const int kx = (nl >> 2) & 1;
    const int qx = quad ^ (nl & 3);

    // x half: fp32 embedding rows (tokens tk[0..3], wave-uniform) OR bf16 h rows;
    // h half: bf16 h rows via LLC atomic loads. Wave w stages rows 4w..4w+3,
    // lane l handles 16B chunk l, stored at chunk l^(r&7) (conflict-free b128).
    auto step = [&](const float* xtab, const int* tk, const unsigned short* xb,
                    const unsigned short* hrow, unsigned short* hout) {
        const int rb = wave << 2;
        if (xtab) {
#pragma unroll
            for (int rr = 0; rr < 4; ++rr) {
                const int rw = rb + rr;
                const float* s = xtab + (size_t)tk[rr] * Ez + (lane << 3);
                float4 lo = *(const float4*)s;
                float4 hi = *(const float4*)(s + 4);
                short8 v;
                v[0] = (short)f2b(lo.x); v[1] = (short)f2b(lo.y);
                v[2] = (short)f2b(lo.z); v[3] = (short)f2b(lo.w);
                v[4] = (short)f2b(hi.x); v[5] = (short)f2b(hi.y);
                v[6] = (short)f2b(hi.z); v[7] = (short)f2b(hi.w);
                *(short8*)(xh_lds + (rw << 10) + ((lane ^ (rw & 7)) << 3)) = v;
            }
        } else {
#pragma unroll
            for (int rr = 0; rr < 4; ++rr) {
                const int rw = rb + rr;
                const unsigned long long* s =
                    (const unsigned long long*)(xb + ((size_t)(bt * 16 + rw) << 9)) + (lane << 1);
                unsigned long long a = __hip_atomic_load(s,
                        __ATOMIC_RELAXED, __HIP_MEMORY_SCOPE_AGENT);
                unsigned long long b = __hip_atomic_load(s + 1,
                        __ATOMIC_RELAXED, __HIP_MEMORY_SCOPE_AGENT);
                *(ull2*)(xh_lds + (rw << 10) + ((lane ^ (rw & 7)) << 3)) = (ull2){a, b};
            }
        }
#pragma unroll
        for (int rr = 0; rr < 4; ++rr) {
            const int rw = rb + rr;
            const unsigned long long* s =
                (const unsigned long long*)(hrow + ((size_t)(bt * 16 + rw) << 9)) + (lane << 1);
            unsigned long long a = __hip_atomic_load(s,
                    __ATOMIC_RELAXED, __HIP_MEMORY_SCOPE_AGENT);
            unsigned long long b = __hip_atomic_load(s + 1,
                    __ATOMIC_RELAXED, __HIP_MEMORY_SCOPE_AGENT);
            *(ull2*)(xh_lds + (rw << 10) + 512 + ((lane ^ (rw & 7)) << 3)) = (ull2){a, b};
        }
        __syncthreads();

        // gates[16 batch][16 rows] for this wave's gate, K=1024; 4 parallel acc chains
        const unsigned short* arE = xh_lds + (nl << 10) + (qx << 3) + (kx << 5);
        const unsigned short* arO = xh_lds + (nl << 10) + (qx << 3) - (kx << 5);
        f32x4 a0 = {0.f, 0.f, 0.f, 0.f}, a1 = a0, a2 = a0, a3 = a0;
#pragma unroll
        for (int kc = 0; kc < 32; kc += 4) {
            short8 x0 = *(const short8*)(arE + ((kc + 0) << 5));
            short8 x1 = *(const short8*)(arO + ((kc + 1) << 5));
            short8 x2 = *(const short8*)(arE + ((kc + 2) << 5));
            short8 x3 = *(const short8*)(arO + ((kc + 3) << 5));
            a0 = __builtin_amdgcn_mfma_f32_16x16x32_bf16(x0, wfrag[kc + 0], a0, 0, 0, 0);
            a1 = __builtin_amdgcn_mfma_f32_16x16x32_bf16(x1, wfrag[kc + 1], a1, 0, 0, 0);
            a2 = __builtin_amdgcn_mfma_f32_16x16x32_bf16(x2, wfrag[kc + 2], a2, 0, 0, 0);
            a3 = __builtin_amdgcn_mfma_f32_16x16x32_bf16(x3, wfrag[kc + 3], a3, 0, 0, 0);
        }
        f32x4 acc = (a0 + a1) + (a2 + a3);
        // C/D: col(n)=lane&15, row(m)=quad*4+i.  Activate + scatter to LDS.
#pragma unroll
        for (int i = 0; i < 4; ++i) {
            float v = acc[i] + bias_r;
            v = (wave == 2) ? tnh(v) : sgm(v);
            gates_lds[wave * 320 + (quad * 4 + i) * 20 + nl] = v;
        }
        __syncthreads();
        if (tid < 128) {   // c/h update: (batch m, unit pair np) per thread
            const int m = tid >> 3, np = tid & 7;
            float hp[2];
#pragma unroll
            for (int j = 0; j < 2; ++j) {
                const int n = 2 * np + j;
                const float iv = gates_lds[      m * 20 + n];
                const float fv = gates_lds[320 + m * 20 + n];
                const float gv = gates_lds[640 + m * 20 + n];
                const float ov = gates_lds[960 + m * 20 + n];
                float c = c_lds[m * 20 + n];
                c = fv * c + iv * gv;
                c_lds[m * 20 + n] = c;
                hp[j] = ov * tnh(c);
            }
            const unsigned pack = (unsigned)f2b(hp[0]) | ((unsigned)f2b(hp[1]) << 16);
            unsigned* dst = (unsigned*)&hout[(size_t)(bt * 16 + m) * 512 + ht * 16 + 2 * np];
            __hip_atomic_store(dst, pack, __ATOMIC_RELAXED, __HIP_MEMORY_SCOPE_AGENT);
        }
    };

    auto hb = [&](int l, int p) { return hbuf + (size_t)(l * 2 + p) * Bz * Hz; };

    // ===== encoder: pipelined rounds; L0 does step t, L1 does step t-1 =====
    load_w(eWih, eWhh, ebih, ebhh);
    for (int t = 0; t <= Sz; ++t) {
        if (lay == 0) {
            if (t < Sz) {
                int tk[4];
#pragma unroll
                for (int rr = 0; rr < 4; ++rr)
                    tk[rr] = X[(bt * 16 + (wave << 2) + rr) * Sz + t];
                step(emb_src, tk, nullptr, hb(0, (t + 1) & 1), hb(0, t & 1));
            }
        } else {
            if (t >= 1) {
                const int s = t - 1;
                step(nullptr, nullptr, hb(0, s & 1),
                     hb(1, (s + 1) & 1), hb(1, s & 1));
            }
        }
        barrier();
    }

    // ===== decoder (states carry over: h via buffer parity, c in LDS) =====
    load_w(dWih, dWhh, dbih, dbhh);
    for (int t = 0; t <= Tz; ++t) {
        if (lay == 0) {
            if (t < Tz) {
                int tk[4];
#pragma unroll
                for (int rr = 0; rr < 4; ++rr)
                    tk[rr] = (t == 0) ? 2 : Y[(bt * 16 + (wave << 2) + rr) * Tz + t - 1];
                step(emb_tgt, tk, nullptr, hb(0, (t + 1) & 1), hb(0, t & 1));
            }
        } else {
            if (t >= 1) {
                const int s = t - 1;
                step(nullptr, nullptr, hb(0, s & 1),
                     hb(1, (s + 1) & 1), hb(1, s & 1));
            }
        }
        if (t < Tz) barrier();   // final round needs no barrier (kernel boundary syncs)
    }
    // decoder L1 final h sits in hb(1,1); FC kernel reads it (kernel-boundary sync).
}

// ===================== 2) FC [64 x 32000] + exp-sum =====================
__global__ __launch_bounds__(NT, 1) void fc_kernel(
    const float* __restrict__ fcW, const float* __restrict__ fcb,
    const unsigned short* __restrict__ hbuf,
    float* __restrict__ logits, float* __restrict__ row_sums)
{
    __shared__ __align__(16) unsigned char smem[66816];
    unsigned short* h_lds = (unsigned short*)smem;          // [64][520] bf16
    float* row_part = (float*)(smem + 64 * 520 * 2);        // [64]

    const int tid  = threadIdx.x;
    const int bid  = blockIdx.x;
    const int wave = tid >> 6;
    const int lane = tid & 63;
    const int nl   = lane & 15;
    const int quad = lane >> 4;

    {   // stage top hidden: hb(1,1) = hbuf + 3*64*512
        const unsigned short* htop = hbuf + (size_t)3 * Bz * Hz;
        const int rr2 = tid >> 2, pp = tid & 3;
        const short8* s = (const short8*)(htop + rr2 * 512 + pp * 128);
        short8* d = (short8*)(h_lds + rr2 * 520 + pp * 128);
#pragma unroll
        for (int i = 0; i < 16; ++i) d[i] = s[i];
    }
    if (tid < 64) row_part[tid] = 0.f;
    __syncthreads();

    const int c0 = bid * 128;                 // this block's 128 vocab cols
    f32x4 acc[8];
#pragma unroll
    for (int ct = 0; ct < 8; ++ct) acc[ct] = (f32x4){0.f, 0.f, 0.f, 0.f};
    const unsigned short* ar = h_lds + (wave * 16 + nl) * 520 + quad * 8;
    const float* bb = fcW + ((size_t)c0 + nl) * 512 + quad * 8;
    for (int kc = 0; kc < 16; ++kc) {
        short8 a = *(const short8*)(ar + kc * 32);
#pragma unroll
        for (int ct = 0; ct < 8; ++ct) {
            const float* bp = bb + (size_t)ct * 16 * 512 + kc * 32;
            float4 lo = *(const float4*)(bp);
            float4 hi = *(const float4*)(bp + 4);
            short8 b;
            b[0] = (short)f2b(lo.x); b[1] = (short)f2b(lo.y);
            b[2] = (short)f2b(lo.z); b[3] = (short)f2b(lo.w);
            b[4] = (short)f2b(hi.x); b[5] = (short)f2b(hi.y);
            b[6] = (short)f2b(hi.z); b[7] = (short)f2b(hi.w);
            acc[ct] = __builtin_amdgcn_mfma_f32_16x16x32_bf16(a, b, acc[ct], 0, 0, 0);
        }
    }
    float ls[4] = {0.f, 0.f, 0.f, 0.f};
#pragma unroll
    for (int ct = 0; ct < 8; ++ct) {
        const int col = c0 + ct * 16 + nl;
        const float bias = fcb[col];
#pragma unroll
        for (int i = 0; i < 4; ++i) {
            const float lg = acc[ct][i] + bias;
            logits[(size_t)(wave * 16 + quad * 4 + i) * VT + col] = lg;
            ls[i] += __expf(lg);     // |logit| <= ~41 -> no overflow, max-shift unneeded
        }
    }
#pragma unroll
    for (int i = 0; i < 4; ++i)
        atomicAdd(&row_part[wave * 16 + quad * 4 + i], ls[i]);
    __syncthreads();
    if (tid < 64) atomicAdd(&row_sums[tid], row_part[tid]);
}

// ===================== 3) normalize: out = logits - log(sum) =====================
__global__ __launch_bounds__(NT) void norm_kernel(
    const float* __restrict__ logits, const float* __restrict__ row_sums,
    float* __restrict__ out)
{
    const int idx = blockIdx.x * NT + threadIdx.x;   // grid covers 64*32000 exactly
    const int row = idx / VT;
    out[idx] = logits[idx] - __logf(row_sums[row]);
}

extern "C" void kernel_launch(void* const* d_in, const int* in_sizes, int n_in,
                              void* d_out, int out_size, void* d_ws, size_t ws_size,
                              hipStream_t stream) {
    const int* X = (const int*)d_in[0];
    const int* Y = (const int*)d_in[1];
    const float* emb_src = (const float*)d_in[2];
    const float* emb_tgt = (const float*)d_in[3];
    const float* eWih = (const float*)d_in[4];
    const float* eWhh = (const float*)d_in[5];
    const float* ebih = (const float*)d_in[6];
    const float* ebhh = (const float*)d_in[7];
    const float* dWih = (const float*)d_in[8];
    const float* dWhh = (const float*)d_in[9];
    const float* dbih = (const float*)d_in[10];
    const float* dbhh = (const float*)d_in[11];
    const float* fcW = (const float*)d_in[12];
    const float* fcb = (const float*)d_in[13];
    float* out = (float*)d_out;

    // ws layout: [0,256KB) bf16 h buffers; [256KB,+256B) row_sums;
    //            [260KB,+1KB) barrier state; [512KB,+8.192MB) fp32 logits
    unsigned short* hbuf = (unsigned short*)d_ws;
    float* row_sums = (float*)((char*)d_ws + 262144);
    unsigned* bars  = (unsigned*)((char*)d_ws + 266240);
    float* logits   = (float*)((char*)d_ws + 524288);

    init_kernel<<<dim3(64), dim3(NT), 0, stream>>>((unsigned*)hbuf, row_sums, bars);

    void* args[] = {&X, &Y, &emb_src, &emb_tgt, &eWih, &eWhh, &ebih, &ebhh,
                    &dWih, &dWhh, &dbih, &dbhh, &hbuf, &bars};
    hipLaunchCooperativeKernel(reinterpret_cast<void*>(scan_kernel),
                               dim3(NB), dim3(NT), args, 0, stream);

    fc_kernel<<<dim3(VT / 128), dim3(NT), 0, stream>>>(fcW, fcb, hbuf, logits, row_sums);

    norm_kernel<<<dim3((Bz * VT) / NT), dim3(NT), 0, stream>>>(logits, row_sums, out);
}